// Round 8
// baseline (7467.411 us; speedup 1.0000x reference)
//
#include <hip/hip_runtime.h>

#define T_LEN 512
#define BATCH 64
#define HID   512
#define EMB   512
#define NWG   256
#define TPB   512
#define RING_SLOT (HID * BATCH)   // 32768 floats per slot, layout [j][b]

// ---- grid barrier state (lives in d_ws, zeroed by init kernel) ----
// Monotonic counters (never reset): leaf[g] gets 16 incs/slot, root gets 16.
// Release fans out: epoch (root winner) -> gep[g] (group winners).
struct GBar {
  int leaf[16 * 32];   // arrival counter per group, one cacheline apart
  int root; int pad1[31];
  int epoch; int pad2[31];
  int gep[16 * 32];    // per-group release epoch, one cacheline apart
};

__global__ void init_ws_kernel(int* ws, int n) {
  int stride = gridDim.x * blockDim.x;
  for (int i = blockIdx.x * blockDim.x + threadIdx.x; i < n; i += stride) ws[i] = 0;
}

__device__ __forceinline__ float sigm(float x)      { return 1.f / (1.f + __expf(-x)); }
// saturation-safe tanh: x->+inf => 1, x->-inf => -1, no inf/inf NaN
__device__ __forceinline__ float tanh_fast(float x) { return 1.f - 2.f / (__expf(2.f * x) + 1.f); }

// coherent (device-scope, cache-bypassing) scalar store — rings are written
// through to the IF coherence point; no L2 line is ever allocated for them
// on the writer side, so readers only have to kill their OWN cached copies.
__device__ __forceinline__ void cstore(float* p, float v) {
  __hip_atomic_store(p, v, __ATOMIC_RELAXED, __HIP_MEMORY_SCOPE_AGENT);
}

// acc (scalar) += dot(xv, wv)
#define DOT_ACC(a, xv, wv) \
  a = fmaf((xv).w, (wv).w, fmaf((xv).z, (wv).z, fmaf((xv).y, (wv).y, fmaf((xv).x, (wv).x, (a)))))
// acc (float4 over b) += s * v (float4 over b)
#define AXPY4(acc, s, v) do { \
  (acc).x = fmaf((s), (v).x, (acc).x); \
  (acc).y = fmaf((s), (v).y, (acc).y); \
  (acc).z = fmaf((s), (v).z, (acc).z); \
  (acc).w = fmaf((s), (v).w, (acc).w); } while (0)

__global__ __launch_bounds__(TPB, 2) void lstm_pipe(
    const int* __restrict__ src, const int* __restrict__ sen_len,
    const float* __restrict__ emb,
    const float* __restrict__ Wih0, const float* __restrict__ Whh0,
    const float* __restrict__ bih0, const float* __restrict__ bhh0,
    const float* __restrict__ Wih1, const float* __restrict__ Whh1,
    const float* __restrict__ bih1, const float* __restrict__ bhh1,
    float* __restrict__ out,
    int* __restrict__ barp, float* __restrict__ h0ring, float* __restrict__ h1ring)
{
  extern __shared__ char smem_raw[];
  float4* WlV  = (float4*)smem_raw;            // 4096 float4 = 64 KB: [kc][16 rows]
  float*  part = (float*)(smem_raw + 65536);   // 8192 floats = 32 KB: [kh][row][b]
  GBar* bar = (GBar*)barp;

  const int wg    = blockIdx.x;
  const int layer = wg >> 7;    // 0: WGs 0..127 (layer0 @ t=s), 1: WGs 128..255 (layer1 @ t=s-1)
  const int w     = wg & 127;   // owns hidden units j in [4w, 4w+4)
  const int tid   = threadIdx.x;
  const int kh    = tid >> 6;   // 0..7  K-segment of 128
  const int lane  = tid & 63;
  const int bg    = lane >> 2;  // 0..15 batch-group (4 batches)
  const int rg    = lane & 3;   // 0..3  j within WG
  const int b0    = bg << 2;    // batches b0..b0+3 (contiguous)
  const int k0    = kh << 7;    // K range [k0, k0+128)

  const float* Wih = layer ? Wih1 : Wih0;
  const float* Whh = layer ? Whh1 : Whh0;

  // Stage 16 rows x 1024 K of fused [Wih | Whh] weights into LDS, [kc][16] float4.
  for (int idx = tid; idx < 4096; idx += TPB) {
    int rowl = idx & 15;          // q*4 + rjj
    int kc   = idx >> 4;          // 0..255
    int q = rowl >> 2, rjj = rowl & 3;
    int grow = q * HID + (w << 2) + rjj;   // global gate row
    int k4 = kc << 2;
    float4 v;
    if (k4 < EMB) v = *(const float4*)(Wih + (size_t)grow * EMB + k4);
    else          v = *(const float4*)(Whh + (size_t)grow * HID + (k4 - EMB));
    WlV[kc * 16 + rowl] = v;
  }

  // Activation-phase identity: threads 0..255 own cell (jj, b); c lives here.
  const int p_b  = tid & 63;
  const int p_jj = (tid >> 6) & 3;
  const int p_jg = (w << 2) + p_jj;
  float bias4[4] = {0.f, 0.f, 0.f, 0.f};
  float c = 0.f;
  int   slen = -2;
  if (tid < 256) {
#pragma unroll
    for (int q = 0; q < 4; ++q) {
      int r = q * HID + p_jg;
      bias4[q] = layer ? (bih1[r] + bhh1[r]) : (bih0[r] + bhh0[r]);
    }
    slen = sen_len[p_b];
  }
  __syncthreads();

  for (int s = 0; s <= T_LEN; ++s) {
    const bool active = (layer == 0) ? (s < T_LEN) : (s >= 1);
    if (active) {
      const int t = (layer == 0) ? s : (s - 1);
      float4 acc[4];
#pragma unroll
      for (int q = 0; q < 4; ++q) acc[q] = make_float4(0.f, 0.f, 0.f, 0.f);

      if (layer == 0 && kh < 4) {
        // ---- embedding-gather mode: read-only data, normal cached loads ----
        const int* st = src + t * BATCH + b0;
        const float* e0 = emb + (size_t)st[0] * EMB;
        const float* e1 = emb + (size_t)st[1] * EMB;
        const float* e2 = emb + (size_t)st[2] * EMB;
        const float* e3 = emb + (size_t)st[3] * EMB;
#pragma unroll 4
        for (int kk = 0; kk < 128; kk += 4) {
          const int k  = k0 + kk;
          const int kc = k >> 2;
          float4 x0 = *(const float4*)(e0 + k);
          float4 x1 = *(const float4*)(e1 + k);
          float4 x2 = *(const float4*)(e2 + k);
          float4 x3 = *(const float4*)(e3 + k);
#pragma unroll
          for (int q = 0; q < 4; ++q) {
            float4 wq = WlV[kc * 16 + (q << 2) + rg];
            DOT_ACC(acc[q].x, x0, wq);
            DOT_ACC(acc[q].y, x1, wq);
            DOT_ACC(acc[q].z, x2, wq);
            DOT_ACC(acc[q].w, x3, wq);
          }
        }
      } else {
        // ---- transposed-ring mode: PLAIN CACHED float4 loads.  Safe because
        // every WG ran an agent-acquire (buffer_inv, L1+L2) after the barrier
        // release of the slot in which this data was produced, and ring writes
        // never allocate into L2 (sc0 sc1 write-through). After first touch
        // these are L2 hits — coherent-read IF traffic drops ~25x.
        const float* xT;
        if (layer == 0) {
          xT = h0ring + ((s + 1) & 1) * RING_SLOT + (k0 - EMB) * BATCH;
        } else if (kh < 4) {
          xT = h0ring + ((s - 1) & 1) * RING_SLOT + k0 * BATCH;
        } else {
          xT = h1ring + ((s - 1) & 1) * RING_SLOT + (k0 - EMB) * BATCH;
        }
        const float* p = xT + b0;
#pragma unroll 4
        for (int kk = 0; kk < 128; kk += 4) {
          const int kc = (k0 + kk) >> 2;
          float4 r0 = *(const float4*)(p + (kk + 0) * BATCH);
          float4 r1 = *(const float4*)(p + (kk + 1) * BATCH);
          float4 r2 = *(const float4*)(p + (kk + 2) * BATCH);
          float4 r3 = *(const float4*)(p + (kk + 3) * BATCH);
#pragma unroll
          for (int q = 0; q < 4; ++q) {
            float4 wq = WlV[kc * 16 + (q << 2) + rg];
            AXPY4(acc[q], wq.x, r0);
            AXPY4(acc[q], wq.y, r1);
            AXPY4(acc[q], wq.z, r2);
            AXPY4(acc[q], wq.w, r3);
          }
        }
      }
      // write partials: part[kh][row][b], row = q*4+rg, b = b0..b0+3
#pragma unroll
      for (int q = 0; q < 4; ++q)
        *(float4*)(part + (kh << 10) + (((q << 2) + rg) << 6) + b0) = acc[q];
    }

    __syncthreads();  // partials visible

    if (active && tid < 256) {
      float g4[4];
#pragma unroll
      for (int q = 0; q < 4; ++q) {
        float a = bias4[q];
        const int base = (((q << 2) + p_jj) << 6) + p_b;
#pragma unroll
        for (int kk = 0; kk < 8; ++kk) a += part[(kk << 10) + base];
        g4[q] = a;
      }
      float ig = sigm(g4[0]), fg = sigm(g4[1]), gg = tanh_fast(g4[2]), og = sigm(g4[3]);
      c = fmaf(fg, c, ig * gg);
      float h = og * tanh_fast(c);
      float* ring = (layer == 0 ? h0ring : h1ring) + (s & 1) * RING_SLOT;
      cstore(ring + p_jg * BATCH + p_b, h);   // coherent store [j][b], write-through
      if (layer == 1) {
        const int t = s - 1;
        if (t == slen - 1) out[p_b * HID + p_jg] = h;
      }
    }

    // ---- hierarchical grid barrier, all-RELAXED, monotonic counters ----
    // __syncthreads() drains vmcnt(0): every coherent h-store is committed at
    // the IF coherence point before tid0's arrival increment.
    __syncthreads();
    if (tid == 0) {
      const int target = s + 1;
      int* leafp = &bar->leaf[(wg >> 4) * 32];
      int* gepp  = &bar->gep[(wg >> 4) * 32];
      int prev = __hip_atomic_fetch_add(leafp, 1, __ATOMIC_RELAXED, __HIP_MEMORY_SCOPE_AGENT);
      if ((prev & 15) == 15) {   // 16th arrival of this slot in this group
        int r = __hip_atomic_fetch_add(&bar->root, 1, __ATOMIC_RELAXED, __HIP_MEMORY_SCOPE_AGENT);
        if ((r & 15) == 15) {    // 16th group — release everyone
          __hip_atomic_store(&bar->epoch, target, __ATOMIC_RELAXED, __HIP_MEMORY_SCOPE_AGENT);
        } else {
          while (__hip_atomic_load(&bar->epoch, __ATOMIC_RELAXED, __HIP_MEMORY_SCOPE_AGENT) < target)
            __builtin_amdgcn_s_sleep(1);
        }
        __hip_atomic_store(gepp, target, __ATOMIC_RELAXED, __HIP_MEMORY_SCOPE_AGENT);
      } else {
        while (__hip_atomic_load(gepp, __ATOMIC_RELAXED, __HIP_MEMORY_SCOPE_AGENT) < target)
          __builtin_amdgcn_s_sleep(1);
      }
    }
    // ---- single agent-acquire per WG: wave 0 invalidates L1 (per-CU) and
    // L2 (per-XCD) — physically clears stale ring lines for ALL waves of
    // this WG. s_waitcnt vmcnt(0) after the fence ensures the buffer_inv
    // has completed (cache ops are vmcnt-tracked) before __syncthreads()
    // lets the other waves issue cached ring loads.
    if (tid < 64) {
      __builtin_amdgcn_fence(__ATOMIC_ACQUIRE, "agent");
      asm volatile("s_waitcnt vmcnt(0)" ::: "memory");
    }
    __syncthreads();
  }
}

extern "C" void kernel_launch(void* const* d_in, const int* in_sizes, int n_in,
                              void* d_out, int out_size, void* d_ws, size_t ws_size,
                              hipStream_t stream) {
  const int*   src  = (const int*)d_in[0];
  const int*   slen = (const int*)d_in[1];
  const float* emb  = (const float*)d_in[2];
  const float* Wih0 = (const float*)d_in[3];
  const float* Whh0 = (const float*)d_in[4];
  const float* bih0 = (const float*)d_in[5];
  const float* bhh0 = (const float*)d_in[6];
  const float* Wih1 = (const float*)d_in[7];
  const float* Whh1 = (const float*)d_in[8];
  const float* bih1 = (const float*)d_in[9];
  const float* bhh1 = (const float*)d_in[10];
  float* out = (float*)d_out;

  int*   bar    = (int*)d_ws;
  float* h0ring = (float*)((char*)d_ws + 8192);
  float* h1ring = h0ring + 2 * RING_SLOT;

  // zero barrier state + all 4 ring slots (ws is poisoned 0xAA before every launch)
  int zero_ints = (8192 + 4 * RING_SLOT * 4) / 4;
  hipLaunchKernelGGL(init_ws_kernel, dim3(64), dim3(256), 0, stream, (int*)d_ws, zero_ints);

  (void)hipFuncSetAttribute((const void*)lstm_pipe,
                            hipFuncAttributeMaxDynamicSharedMemorySize, 98304);

  hipLaunchKernelGGL(lstm_pipe, dim3(NWG), dim3(TPB), 98304, stream,
                     src, slen, emb, Wih0, Whh0, bih0, bhh0, Wih1, Whh1, bih1, bhh1,
                     out, bar, h0ring, h1ring);
}